// Round 6
// baseline (278.194 us; speedup 1.0000x reference)
//
#include <hip/hip_runtime.h>
#include <hip/hip_bf16.h>
#include <stdint.h>
#include <type_traits>

typedef unsigned short u16;
typedef __bf16 bf16x8 __attribute__((ext_vector_type(8)));
typedef float f32x4 __attribute__((ext_vector_type(4)));

#define M_TOT 8192   // B*S
#define N_TOT 4096   // reduction dim
#define K_TOT 4096   // output dim
#define BM 256
#define BN 256
#define BK 64
#define NT 64        // N_TOT / BK

// LDS geometry in u16 elements: [slot][A:2 halves | B:2 halves][128][64]
#define HALF_EL 8192     // 128 rows * 64 cols
#define B_OFF   16384
#define SLOT_EL 32768    // 64 KiB per slot

template <int V> using ic = std::integral_constant<int, V>;

__device__ __forceinline__ u16 f2bf(float f) {
    union { float f; uint32_t u; } v; v.f = f;
    uint32_t u = v.u;
    return (u16)((u + 0x7fffu + ((u >> 16) & 1u)) >> 16);
}

// ---- pre-pass 1: x fp32 -> bf16 ----------------------------------------------
__global__ __launch_bounds__(256) void cvt_x_kernel(const float* __restrict__ x,
                                                    u16* __restrict__ xb) {
    const int i = blockIdx.x * blockDim.x + threadIdx.x;
    const float4* p = (const float4*)x + (size_t)i * 2;
    float4 v0 = p[0], v1 = p[1];
    uint4 o;
    o.x = (uint32_t)f2bf(v0.x) | ((uint32_t)f2bf(v0.y) << 16);
    o.y = (uint32_t)f2bf(v0.z) | ((uint32_t)f2bf(v0.w) << 16);
    o.z = (uint32_t)f2bf(v1.x) | ((uint32_t)f2bf(v1.y) << 16);
    o.w = (uint32_t)f2bf(v1.z) | ((uint32_t)f2bf(v1.w) << 16);
    *((uint4*)(xb + (size_t)i * 8)) = o;
}

// ---- pre-pass 2: dequantize W_q -> bf16 --------------------------------------
__global__ __launch_bounds__(256) void deq_w_kernel(const int* __restrict__ wq,
                                                    const float* __restrict__ scales,
                                                    const float* __restrict__ zeros,
                                                    const float* __restrict__ mu1,
                                                    const float* __restrict__ mu2,
                                                    u16* __restrict__ wb) {
    const int i = blockIdx.x * blockDim.x + threadIdx.x;
    const int k  = i >> 9;
    const int n0 = (i & 511) << 3;
    const int g  = n0 >> 6;
    const float z  = zeros[k * 64 + g];
    const float sm = scales[k * 64 + g] * mu2[k];
    const int4* qp = (const int4*)(wq + (size_t)k * N_TOT + n0);
    int4 q0 = qp[0], q1 = qp[1];
    const float4* mp = (const float4*)(mu1 + n0);
    float4 u0 = mp[0], u1 = mp[1];
    uint4 o;
    o.x = (uint32_t)f2bf(((float)q0.x - z) * sm * u0.x) |
          ((uint32_t)f2bf(((float)q0.y - z) * sm * u0.y) << 16);
    o.y = (uint32_t)f2bf(((float)q0.z - z) * sm * u0.z) |
          ((uint32_t)f2bf(((float)q0.w - z) * sm * u0.w) << 16);
    o.z = (uint32_t)f2bf(((float)q1.x - z) * sm * u1.x) |
          ((uint32_t)f2bf(((float)q1.y - z) * sm * u1.y) << 16);
    o.w = (uint32_t)f2bf(((float)q1.z - z) * sm * u1.z) |
          ((uint32_t)f2bf(((float)q1.w - z) * sm * u1.w) << 16);
    *((uint4*)(wb + (size_t)k * N_TOT + n0)) = o;
}

// ---- main GEMM: 256x256 8-phase, deep counted-vmcnt pipeline (m201-faithful) --
// 8 waves (2M x 4N), per-wave out 128x64, BK=64, double-buffered LDS.
// Gray-code quadrants: p0=(0,0) p1=(0,1) p2=(1,1) p3=(1,0); fragments cached in
// regs, so ds_reads: p0: A0+B0 (12), p1: B1 (4), p2: A1 (8), p3: none.
// LDS half-tile deaths: A0,B0 @p0; B1 @p1; A1 @p2.
// Staging (1 half-tile = 2 gload_lds per phase, issued strictly post-death):
//   p0 -> (t+1).A1 [other slot; dead since (t-1).p2]
//   p1 -> (t+2).A0 [this slot; died t.p0]
//   p2 -> (t+2).B0 [this slot; died t.p0]
//   p3 -> (t+2).B1 [this slot; died t.p1]
// One vmcnt(6) per tile at p3: drains {t-1.p1,p2,p3, t.p0} = ALL of tile t+1's
// buffers; leaves the 3 newest (tile t+2, 3-6 phases in flight) outstanding.
// Peel: vmcnt(0) at t >= NT-2. Prologue: tile0 x4 + tile1 A0,B0,B1; vmcnt(6).
// LDS XOR swizzle (proven R2): physical col = logical ^ ((row&7)*8 elems);
// linear gload_lds dest + inverse-swizzled global source + swizzled ds_read.
__global__ __launch_bounds__(512, 2) void gemm_kernel(const u16* __restrict__ Xb,
                                                      const u16* __restrict__ Wb,
                                                      const float* __restrict__ bias,
                                                      float* __restrict__ out) {
    __shared__ __align__(16) u16 lds[2 * SLOT_EL];   // 128 KiB

    // XCD-bijective swizzle: nwg = 512, divisible by 8
    const int bid = blockIdx.x;
    const int cpx = gridDim.x >> 3;
    const int swz = (bid & 7) * cpx + (bid >> 3);
    const int bm = swz >> 4;    // 32 M-tiles
    const int bn = swz & 15;    // 16 out-tiles

    const int tid  = threadIdx.x;
    const int w    = tid >> 6;
    const int lane = tid & 63;
    const int wm = w >> 2, wn = w & 3;

    // --- staging addressing: lane l, issue i covers LDS row (w*16 + i*8 + (l>>3)),
    // physical col (l&7)*16B; global col pre-swizzled: ((l&7)^(l>>3))*8 elems.
    const int scol = (((lane & 7) ^ (lane >> 3)) << 3);
    const u16* aS = Xb + (size_t)(bm * BM + w * 16 + (lane >> 3)) * N_TOT + scol;
    const u16* bS = Wb + (size_t)(bn * BN + w * 16 + (lane >> 3)) * N_TOT + scol;

    auto stageA = [&](int slot, int h, int u) {
        const u16* s = aS + (size_t)(h * 128) * N_TOT + u * BK;
        u16* d = &lds[slot * SLOT_EL + h * HALF_EL + w * 1024];   // wave-uniform
        __builtin_amdgcn_global_load_lds(
            (const __attribute__((address_space(1))) uint32_t*)s,
            (__attribute__((address_space(3))) uint32_t*)d, 16, 0, 0);
        __builtin_amdgcn_global_load_lds(
            (const __attribute__((address_space(1))) uint32_t*)(s + (size_t)8 * N_TOT),
            (__attribute__((address_space(3))) uint32_t*)(d + 512), 16, 0, 0);
    };
    auto stageB = [&](int slot, int h, int u) {
        const u16* s = bS + (size_t)(h * 128) * N_TOT + u * BK;
        u16* d = &lds[slot * SLOT_EL + B_OFF + h * HALF_EL + w * 1024];
        __builtin_amdgcn_global_load_lds(
            (const __attribute__((address_space(1))) uint32_t*)s,
            (__attribute__((address_space(3))) uint32_t*)d, 16, 0, 0);
        __builtin_amdgcn_global_load_lds(
            (const __attribute__((address_space(1))) uint32_t*)(s + (size_t)8 * N_TOT),
            (__attribute__((address_space(3))) uint32_t*)(d + 512), 16, 0, 0);
    };

    // --- fragment read addressing (u16 elements) ---
    const int cc0 = (((lane >> 4) << 3)) ^ ((lane & 7) << 3);
    const int rA  = ((wm << 4) + (lane & 15)) << 6;
    const int rB  = ((wn << 4) + (lane & 15)) << 6;

    f32x4 acc[2][2][4][2] = {};
    bf16x8 af[2][4][2];   // [mh][j][ks]
    bf16x8 bfr[2][2][2];  // [nh][j2][ks]

    auto phase = [&](auto Pc, int t) {
        constexpr int P = Pc.value;
        constexpr int mh = (P >= 2) ? 1 : 0;               // gray: 00,01,11,10
        constexpr int nh = (P == 1 || P == 2) ? 1 : 0;
        const int slot = (t & 1) * SLOT_EL;

        if constexpr (P == 0) {
            #pragma unroll
            for (int j = 0; j < 4; ++j) {
                af[0][j][0] = *(const bf16x8*)&lds[slot + rA + j * 2048 + cc0];
                af[0][j][1] = *(const bf16x8*)&lds[slot + rA + j * 2048 + (cc0 ^ 32)];
            }
            #pragma unroll
            for (int j2 = 0; j2 < 2; ++j2) {
                bfr[0][j2][0] = *(const bf16x8*)&lds[slot + B_OFF + rB + j2 * 4096 + cc0];
                bfr[0][j2][1] = *(const bf16x8*)&lds[slot + B_OFF + rB + j2 * 4096 + (cc0 ^ 32)];
            }
        } else if constexpr (P == 1) {
            #pragma unroll
            for (int j2 = 0; j2 < 2; ++j2) {
                bfr[1][j2][0] = *(const bf16x8*)&lds[slot + B_OFF + HALF_EL + rB + j2 * 4096 + cc0];
                bfr[1][j2][1] = *(const bf16x8*)&lds[slot + B_OFF + HALF_EL + rB + j2 * 4096 + (cc0 ^ 32)];
            }
        } else if constexpr (P == 2) {
            #pragma unroll
            for (int j = 0; j < 4; ++j) {
                af[1][j][0] = *(const bf16x8*)&lds[slot + HALF_EL + rA + j * 2048 + cc0];
                af[1][j][1] = *(const bf16x8*)&lds[slot + HALF_EL + rA + j * 2048 + (cc0 ^ 32)];
            }
        }

        // staging, strictly post-death targets (see header)
        if constexpr (P == 0) { if (t + 1 < NT) stageA((t + 1) & 1, 1, t + 1); }
        if constexpr (P == 1) { if (t + 2 < NT) stageA(t & 1, 0, t + 2); }
        if constexpr (P == 2) { if (t + 2 < NT) stageB(t & 1, 0, t + 2); }
        if constexpr (P == 3) { if (t + 2 < NT) stageB(t & 1, 1, t + 2); }

        if constexpr (P == 0)
            asm volatile("s_waitcnt lgkmcnt(8)" ::: "memory");  // throttle 12-read phase

        __builtin_amdgcn_s_barrier();
        asm volatile("s_waitcnt lgkmcnt(0)" ::: "memory");
        __builtin_amdgcn_sched_barrier(0);
        __builtin_amdgcn_s_setprio(1);
        #pragma unroll
        for (int ks = 0; ks < 2; ++ks)
            #pragma unroll
            for (int j = 0; j < 4; ++j)
                #pragma unroll
                for (int j2 = 0; j2 < 2; ++j2)
                    acc[mh][nh][j][j2] = __builtin_amdgcn_mfma_f32_16x16x32_bf16(
                        af[mh][j][ks], bfr[nh][j2][ks], acc[mh][nh][j][j2], 0, 0, 0);
        __builtin_amdgcn_s_setprio(0);
        if constexpr (P == 3) {
            if (t < NT - 2) asm volatile("s_waitcnt vmcnt(6)" ::: "memory");
            else            asm volatile("s_waitcnt vmcnt(0)" ::: "memory");
        }
        __builtin_amdgcn_s_barrier();
    };

    // prologue: tile0 complete, then tile1's A0,B0,B1 (3 newest stay in flight)
    stageA(0, 0, 0); stageB(0, 0, 0); stageB(0, 1, 0); stageA(0, 1, 0);
    stageA(1, 0, 1); stageB(1, 0, 1); stageB(1, 1, 1);
    asm volatile("s_waitcnt vmcnt(6)" ::: "memory");
    __builtin_amdgcn_s_barrier();

    for (int t = 0; t < NT; ++t) {
        phase(ic<0>{}, t);
        phase(ic<1>{}, t);
        phase(ic<2>{}, t);
        phase(ic<3>{}, t);
    }

    // epilogue: C/D layout col = lane&15 (out-dim), row = (lane>>4)*4 + rr (M)
    #pragma unroll
    for (int mh_ = 0; mh_ < 2; ++mh_)
        #pragma unroll
        for (int j = 0; j < 4; ++j)
            #pragma unroll
            for (int rr = 0; rr < 4; ++rr) {
                const int row = bm * BM + mh_ * 128 + j * 32 + wm * 16 + ((lane >> 4) << 2) + rr;
                float* orow = out + (size_t)row * K_TOT;
                #pragma unroll
                for (int nh_ = 0; nh_ < 2; ++nh_)
                    #pragma unroll
                    for (int j2 = 0; j2 < 2; ++j2) {
                        const int col = bn * BN + nh_ * 128 + j2 * 64 + wn * 16 + (lane & 15);
                        orow[col] = acc[mh_][nh_][j][j2][rr] + bias[col];
                    }
            }
}

extern "C" void kernel_launch(void* const* d_in, const int* in_sizes, int n_in,
                              void* d_out, int out_size, void* d_ws, size_t ws_size,
                              hipStream_t stream) {
    const float* x      = (const float*)d_in[0];
    const float* scales = (const float*)d_in[1];
    const float* zeros  = (const float*)d_in[2];
    const float* mu1    = (const float*)d_in[3];
    const float* mu2    = (const float*)d_in[4];
    const float* bias   = (const float*)d_in[5];
    const int*   wq     = (const int*)d_in[6];
    float* out = (float*)d_out;

    u16* xb = (u16*)d_ws;                                 // 64 MiB
    u16* wb = (u16*)d_ws + (size_t)M_TOT * N_TOT;         // 32 MiB

    cvt_x_kernel<<<(M_TOT * N_TOT / 8) / 256, 256, 0, stream>>>(x, xb);
    deq_w_kernel<<<(K_TOT * N_TOT / 8) / 256, 256, 0, stream>>>(wq, scales, zeros, mu1, mu2, wb);
    gemm_kernel<<<(M_TOT / BM) * (K_TOT / BN), 512, 0, stream>>>(xb, wb, bias, out);
}

// Round 7
// 271.018 us; speedup vs baseline: 1.0265x; 1.0265x over previous
//
#include <hip/hip_runtime.h>
#include <hip/hip_bf16.h>
#include <stdint.h>
#include <type_traits>

typedef unsigned short u16;
typedef __bf16 bf16x8 __attribute__((ext_vector_type(8)));
typedef float f32x4 __attribute__((ext_vector_type(4)));

#define M_TOT 8192   // B*S
#define N_TOT 4096   // reduction dim
#define K_TOT 4096   // output dim
#define BM 256
#define BN 256
#define BK 64
#define NT 64        // N_TOT / BK

// LDS geometry in u16 elements: [slot][A:2 halves | B:2 halves][128][64]
#define HALF_EL 8192     // 128 rows * 64 cols
#define B_OFF   16384
#define SLOT_EL 32768    // 64 KiB per slot

template <int V> using ic = std::integral_constant<int, V>;
template <bool V> using bc = std::integral_constant<bool, V>;

__device__ __forceinline__ u16 f2bf(float f) {
    union { float f; uint32_t u; } v; v.f = f;
    uint32_t u = v.u;
    return (u16)((u + 0x7fffu + ((u >> 16) & 1u)) >> 16);
}

// ---- pre-pass 1: x fp32 -> bf16 ----------------------------------------------
__global__ __launch_bounds__(256) void cvt_x_kernel(const float* __restrict__ x,
                                                    u16* __restrict__ xb) {
    const int i = blockIdx.x * blockDim.x + threadIdx.x;
    const float4* p = (const float4*)x + (size_t)i * 2;
    float4 v0 = p[0], v1 = p[1];
    uint4 o;
    o.x = (uint32_t)f2bf(v0.x) | ((uint32_t)f2bf(v0.y) << 16);
    o.y = (uint32_t)f2bf(v0.z) | ((uint32_t)f2bf(v0.w) << 16);
    o.z = (uint32_t)f2bf(v1.x) | ((uint32_t)f2bf(v1.y) << 16);
    o.w = (uint32_t)f2bf(v1.z) | ((uint32_t)f2bf(v1.w) << 16);
    *((uint4*)(xb + (size_t)i * 8)) = o;
}

// ---- pre-pass 2: dequantize W_q -> bf16 --------------------------------------
__global__ __launch_bounds__(256) void deq_w_kernel(const int* __restrict__ wq,
                                                    const float* __restrict__ scales,
                                                    const float* __restrict__ zeros,
                                                    const float* __restrict__ mu1,
                                                    const float* __restrict__ mu2,
                                                    u16* __restrict__ wb) {
    const int i = blockIdx.x * blockDim.x + threadIdx.x;
    const int k  = i >> 9;
    const int n0 = (i & 511) << 3;
    const int g  = n0 >> 6;
    const float z  = zeros[k * 64 + g];
    const float sm = scales[k * 64 + g] * mu2[k];
    const int4* qp = (const int4*)(wq + (size_t)k * N_TOT + n0);
    int4 q0 = qp[0], q1 = qp[1];
    const float4* mp = (const float4*)(mu1 + n0);
    float4 u0 = mp[0], u1 = mp[1];
    uint4 o;
    o.x = (uint32_t)f2bf(((float)q0.x - z) * sm * u0.x) |
          ((uint32_t)f2bf(((float)q0.y - z) * sm * u0.y) << 16);
    o.y = (uint32_t)f2bf(((float)q0.z - z) * sm * u0.z) |
          ((uint32_t)f2bf(((float)q0.w - z) * sm * u0.w) << 16);
    o.z = (uint32_t)f2bf(((float)q1.x - z) * sm * u1.x) |
          ((uint32_t)f2bf(((float)q1.y - z) * sm * u1.y) << 16);
    o.w = (uint32_t)f2bf(((float)q1.z - z) * sm * u1.z) |
          ((uint32_t)f2bf(((float)q1.w - z) * sm * u1.w) << 16);
    *((uint4*)(wb + (size_t)k * N_TOT + n0)) = o;
}

// ---- main GEMM: R6 schedule + compile-time-slot addressing --------------------
// Schedule identical to R6 (gray-code 4 phases, deep staging, vmcnt(6)).
// New: K-loop unrolled x2 so slot is constexpr; 8 precomputed LDS base
// pointers make every ds_read base+imm (<32KB within slot); global staging
// from an advancing aT/bT pointer with compile-time deltas.
__global__ __launch_bounds__(512, 2) void gemm_kernel(const u16* __restrict__ Xb,
                                                      const u16* __restrict__ Wb,
                                                      const float* __restrict__ bias,
                                                      float* __restrict__ out) {
    __shared__ __align__(16) u16 lds[2 * SLOT_EL];   // 128 KiB

    // XCD-bijective swizzle: nwg = 512, divisible by 8
    const int bid = blockIdx.x;
    const int cpx = gridDim.x >> 3;
    const int swz = (bid & 7) * cpx + (bid >> 3);
    const int bm = swz >> 4;    // 32 M-tiles
    const int bn = swz & 15;    // 16 out-tiles

    const int tid  = threadIdx.x;
    const int w    = tid >> 6;
    const int lane = tid & 63;
    const int wm = w >> 2, wn = w & 3;

    // staging: lane l, issue i covers LDS row (w*16 + i*8 + (l>>3)), physical
    // col (l&7)*16B; global col pre-swizzled: ((l&7)^(l>>3))*8 elems.
    const int scol = (((lane & 7) ^ (lane >> 3)) << 3);
    const u16* aT = Xb + (size_t)(bm * BM + w * 16 + (lane >> 3)) * N_TOT + scol;
    const u16* bT = Wb + (size_t)(bn * BN + w * 16 + (lane >> 3)) * N_TOT + scol;

    u16* const sdA = &lds[w * 1024];
    u16* const sdB = &lds[B_OFF + w * 1024];

    auto gload = [](const u16* s, u16* d) {
        __builtin_amdgcn_global_load_lds(
            (const __attribute__((address_space(1))) uint32_t*)s,
            (__attribute__((address_space(3))) uint32_t*)d, 16, 0, 0);
    };
    // dest slot SL, half H, source delta D elements from aT/bT
    auto stA = [&](auto SlC, auto Hc, auto Dc) {
        const u16* s = aT + (size_t)(Hc.value * 128) * N_TOT + Dc.value;
        u16* d = sdA + SlC.value * SLOT_EL + Hc.value * HALF_EL;
        gload(s, d); gload(s + (size_t)8 * N_TOT, d + 512);
    };
    auto stB = [&](auto SlC, auto Hc, auto Dc) {
        const u16* s = bT + (size_t)(Hc.value * 128) * N_TOT + Dc.value;
        u16* d = sdB + SlC.value * SLOT_EL + Hc.value * HALF_EL;
        gload(s, d); gload(s + (size_t)8 * N_TOT, d + 512);
    };

    // fragment read bases: [slot][ks], all ds_read offsets are sub-32KB imms
    const int cc0 = (((lane >> 4) << 3)) ^ ((lane & 7) << 3);
    const int rA  = ((wm << 4) + (lane & 15)) << 6;
    const int rB  = ((wn << 4) + (lane & 15)) << 6;
    const u16* pAk[2][2];
    const u16* pBk[2][2];
    pAk[0][0] = &lds[rA + cc0];
    pAk[0][1] = &lds[rA + (cc0 ^ 32)];
    pAk[1][0] = pAk[0][0] + SLOT_EL;
    pAk[1][1] = pAk[0][1] + SLOT_EL;
    pBk[0][0] = &lds[B_OFF + rB + cc0];
    pBk[0][1] = &lds[B_OFF + rB + (cc0 ^ 32)];
    pBk[1][0] = pBk[0][0] + SLOT_EL;
    pBk[1][1] = pBk[0][1] + SLOT_EL;

    f32x4 acc[2][2][4][2] = {};
    bf16x8 af[2][4][2];   // [mh][j][ks]
    bf16x8 bfr[2][2][2];  // [nh][j2][ks]

    // one phase: reads -> stage -> [lgkm throttle] -> barrier -> lgkm(0) ->
    // MFMA cluster -> [vmcnt] -> barrier.   (identical ordering to R6)
    auto phase = [&](auto SlotC, auto Pc, auto Sc, auto Vc) {
        constexpr int SL = SlotC.value;
        constexpr int P  = Pc.value;
        constexpr bool S = Sc.value;
        constexpr int V  = Vc.value;
        constexpr int mh = (P >= 2) ? 1 : 0;               // gray: 00,01,11,10
        constexpr int nh = (P == 1 || P == 2) ? 1 : 0;

        if constexpr (P == 0) {
            #pragma unroll
            for (int j = 0; j < 4; ++j) {
                af[0][j][0] = *(const bf16x8*)(pAk[SL][0] + j * 2048);
                af[0][j][1] = *(const bf16x8*)(pAk[SL][1] + j * 2048);
            }
            #pragma unroll
            for (int j2 = 0; j2 < 2; ++j2) {
                bfr[0][j2][0] = *(const bf16x8*)(pBk[SL][0] + j2 * 4096);
                bfr[0][j2][1] = *(const bf16x8*)(pBk[SL][1] + j2 * 4096);
            }
        } else if constexpr (P == 1) {
            #pragma unroll
            for (int j2 = 0; j2 < 2; ++j2) {
                bfr[1][j2][0] = *(const bf16x8*)(pBk[SL][0] + HALF_EL + j2 * 4096);
                bfr[1][j2][1] = *(const bf16x8*)(pBk[SL][1] + HALF_EL + j2 * 4096);
            }
        } else if constexpr (P == 2) {
            #pragma unroll
            for (int j = 0; j < 4; ++j) {
                af[1][j][0] = *(const bf16x8*)(pAk[SL][0] + HALF_EL + j * 2048);
                af[1][j][1] = *(const bf16x8*)(pAk[SL][1] + HALF_EL + j * 2048);
            }
        }

        // staging, strictly post-death (R6 proof). Deltas relative to aT/bT
        // which sit at the EVEN tile of the current pair (parity == SL).
        if constexpr (S) {
            if constexpr (P == 0) stA(ic<SL ^ 1>{}, ic<1>{}, ic<(SL ? 2 : 1) * BK>{});
            if constexpr (P == 1) stA(ic<SL>{},     ic<0>{}, ic<(SL ? 3 : 2) * BK>{});
            if constexpr (P == 2) stB(ic<SL>{},     ic<0>{}, ic<(SL ? 3 : 2) * BK>{});
            if constexpr (P == 3) stB(ic<SL>{},     ic<1>{}, ic<(SL ? 3 : 2) * BK>{});
        }

        if constexpr (P == 0)
            asm volatile("s_waitcnt lgkmcnt(8)" ::: "memory");  // throttle 12-read phase

        __builtin_amdgcn_s_barrier();
        asm volatile("s_waitcnt lgkmcnt(0)" ::: "memory");
        __builtin_amdgcn_sched_barrier(0);
        __builtin_amdgcn_s_setprio(1);
        #pragma unroll
        for (int ks = 0; ks < 2; ++ks)
            #pragma unroll
            for (int j = 0; j < 4; ++j)
                #pragma unroll
                for (int j2 = 0; j2 < 2; ++j2)
                    acc[mh][nh][j][j2] = __builtin_amdgcn_mfma_f32_16x16x32_bf16(
                        af[mh][j][ks], bfr[nh][j2][ks], acc[mh][nh][j][j2], 0, 0, 0);
        __builtin_amdgcn_s_setprio(0);
        if constexpr (V == 6)      asm volatile("s_waitcnt vmcnt(6)" ::: "memory");
        else if constexpr (V == 0) asm volatile("s_waitcnt vmcnt(0)" ::: "memory");
        __builtin_amdgcn_s_barrier();
    };

    auto ktile = [&](auto SlotC, auto Sc, auto Vc) {
        phase(SlotC, ic<0>{}, Sc, ic<-1>{});
        phase(SlotC, ic<1>{}, Sc, ic<-1>{});
        phase(SlotC, ic<2>{}, Sc, ic<-1>{});
        phase(SlotC, ic<3>{}, Sc, Vc);
    };

    // prologue: tile0 complete (8 loads), then tile1's A0,B0,B1 (6 loads);
    // vmcnt(6) drains exactly tile0's four buffers.
    stA(ic<0>{}, ic<0>{}, ic<0>{});  stB(ic<0>{}, ic<0>{}, ic<0>{});
    stB(ic<0>{}, ic<1>{}, ic<0>{});  stA(ic<0>{}, ic<1>{}, ic<0>{});
    stA(ic<1>{}, ic<0>{}, ic<BK>{}); stB(ic<1>{}, ic<0>{}, ic<BK>{});
    stB(ic<1>{}, ic<1>{}, ic<BK>{});
    asm volatile("s_waitcnt vmcnt(6)" ::: "memory");
    __builtin_amdgcn_s_barrier();

    // steady: tiles 0..61 (31 pairs), full staging, counted vmcnt(6)
    for (int it = 0; it < 31; ++it) {
        ktile(ic<0>{}, bc<true>{}, ic<6>{});
        ktile(ic<1>{}, bc<true>{}, ic<6>{});
        aT += 2 * BK;
        bT += 2 * BK;
    }
    // tile 62 (slot 0): stage only p0 -> 63.A1; p3 drains everything
    phase(ic<0>{}, ic<0>{}, bc<true>{},  ic<-1>{});
    phase(ic<0>{}, ic<1>{}, bc<false>{}, ic<-1>{});
    phase(ic<0>{}, ic<2>{}, bc<false>{}, ic<-1>{});
    phase(ic<0>{}, ic<3>{}, bc<false>{}, ic<0>{});
    // tile 63 (slot 1): no staging, no waits pending
    phase(ic<1>{}, ic<0>{}, bc<false>{}, ic<-1>{});
    phase(ic<1>{}, ic<1>{}, bc<false>{}, ic<-1>{});
    phase(ic<1>{}, ic<2>{}, bc<false>{}, ic<-1>{});
    phase(ic<1>{}, ic<3>{}, bc<false>{}, ic<-1>{});

    // epilogue: C/D layout col = lane&15 (out-dim), row = (lane>>4)*4 + rr (M)
    #pragma unroll
    for (int mh_ = 0; mh_ < 2; ++mh_)
        #pragma unroll
        for (int j = 0; j < 4; ++j)
            #pragma unroll
            for (int rr = 0; rr < 4; ++rr) {
                const int row = bm * BM + mh_ * 128 + j * 32 + wm * 16 + ((lane >> 4) << 2) + rr;
                float* orow = out + (size_t)row * K_TOT;
                #pragma unroll
                for (int nh_ = 0; nh_ < 2; ++nh_)
                    #pragma unroll
                    for (int j2 = 0; j2 < 2; ++j2) {
                        const int col = bn * BN + nh_ * 128 + j2 * 64 + wn * 16 + (lane & 15);
                        orow[col] = acc[mh_][nh_][j][j2][rr] + bias[col];
                    }
            }
}

extern "C" void kernel_launch(void* const* d_in, const int* in_sizes, int n_in,
                              void* d_out, int out_size, void* d_ws, size_t ws_size,
                              hipStream_t stream) {
    const float* x      = (const float*)d_in[0];
    const float* scales = (const float*)d_in[1];
    const float* zeros  = (const float*)d_in[2];
    const float* mu1    = (const float*)d_in[3];
    const float* mu2    = (const float*)d_in[4];
    const float* bias   = (const float*)d_in[5];
    const int*   wq     = (const int*)d_in[6];
    float* out = (float*)d_out;

    u16* xb = (u16*)d_ws;                                 // 64 MiB
    u16* wb = (u16*)d_ws + (size_t)M_TOT * N_TOT;         // 32 MiB

    cvt_x_kernel<<<(M_TOT * N_TOT / 8) / 256, 256, 0, stream>>>(x, xb);
    deq_w_kernel<<<(K_TOT * N_TOT / 8) / 256, 256, 0, stream>>>(wq, scales, zeros, mu1, mu2, wb);
    gemm_kernel<<<(M_TOT / BM) * (K_TOT / BN), 512, 0, stream>>>(xb, wb, bias, out);
}